// Round 9
// baseline (484.312 us; speedup 1.0000x reference)
//
#include <hip/hip_runtime.h>
#include <math.h>

#define N_NODES 20000
#define F_IN    128
#define H_HEADS 5
#define HID     320
#define NHID    512
#define NOUT    256
#define G_GRAPHS 200

typedef __attribute__((ext_vector_type(8))) short bf16x8;
typedef __attribute__((ext_vector_type(4))) float f32x4;
typedef __attribute__((ext_vector_type(2))) unsigned short u16x2;

__device__ __forceinline__ unsigned short f2bf(float f) {
    unsigned int u = __float_as_uint(f);
    u += 0x7fffu + ((u >> 16) & 1u);
    return (unsigned short)(u >> 16);
}
__device__ __forceinline__ float bf2f(unsigned short u) {
    return __uint_as_float(((unsigned int)u) << 16);
}

// ---------------- CSR build (dst -> list of src), self-loops included ----------------
__global__ void k_init_cnt(int* cnt) {
    int i = blockIdx.x * 256 + threadIdx.x;
    if (i < N_NODES) cnt[i] = 1;  // self loop
}

__global__ void k_hist(const int* __restrict__ ei, int* cnt, int E) {
    int e = blockIdx.x * 256 + threadIdx.x;
    if (e < E) atomicAdd(&cnt[ei[E + e]], 1);
}

__global__ __launch_bounds__(1024) void k_scan(const int* __restrict__ cnt, int* off, int* cur) {
    __shared__ int part[1024];
    int t = threadIdx.x;
    const int per = (N_NODES + 1023) / 1024;
    int base = t * per;
    int sum = 0;
    for (int i = 0; i < per; ++i) { int idx = base + i; if (idx < N_NODES) sum += cnt[idx]; }
    part[t] = sum;
    __syncthreads();
    for (int s = 1; s < 1024; s <<= 1) {
        int v = (t >= s) ? part[t - s] : 0;
        __syncthreads();
        part[t] += v;
        __syncthreads();
    }
    int run = (t == 0) ? 0 : part[t - 1];
    for (int i = 0; i < per; ++i) {
        int idx = base + i;
        if (idx < N_NODES) { off[idx] = run; cur[idx] = run; run += cnt[idx]; }
    }
    if (t == 1023) off[N_NODES] = part[1023];
}

// merged self-loop + edge fill
__global__ void k_fill(const int* __restrict__ ei, int* cur, int* srcl, int E) {
    int idx = blockIdx.x * 256 + threadIdx.x;
    if (idx < N_NODES) {
        int p = atomicAdd(&cur[idx], 1);
        srcl[p] = idx;
    } else {
        int e = idx - N_NODES;
        if (e < E) {
            int d = ei[E + e];
            int p = atomicAdd(&cur[d], 1);
            srcl[p] = ei[e];
        }
    }
}

// ---------------- conversions ----------------
__global__ void k_cvt(const float* __restrict__ in, unsigned short* __restrict__ outp, int n) {
    int i = blockIdx.x * 256 + threadIdx.x;
    if (i < n) outp[i] = f2bf(in[i]);
}

// all 7 weight packs in one launch: W [K,320] f32 -> Bp [K/8][320][8] bf16
// (n-adjacent 16B chunks: GEMM B-loads become fully coalesced)
__global__ void k_wt_all(const float* __restrict__ s0, const float* __restrict__ s1,
                         const float* __restrict__ s2, const float* __restrict__ s3,
                         const float* __restrict__ s4, const float* __restrict__ s5,
                         const float* __restrict__ s6,
                         unsigned short* __restrict__ d0, unsigned short* __restrict__ d1,
                         unsigned short* __restrict__ d2, unsigned short* __restrict__ d3,
                         unsigned short* __restrict__ d4, unsigned short* __restrict__ d5,
                         unsigned short* __restrict__ d6) {
    int y = blockIdx.y;
    const float* S; unsigned short* D; int K;
    switch (y) {
        case 0: S = s0; D = d0; K = F_IN; break;
        case 1: S = s1; D = d1; K = F_IN; break;
        case 2: S = s2; D = d2; K = HID; break;
        case 3: S = s3; D = d3; K = HID; break;
        case 4: S = s4; D = d4; K = HID; break;
        case 5: S = s5; D = d5; K = HID; break;
        default: S = s6; D = d6; K = HID; break;
    }
    int n_elems = HID * K;
    int i = blockIdx.x * 256 + threadIdx.x;
    if (i < n_elems) {
        int kr = i & 7;
        int t  = i >> 3;          // kg*320 + n
        int n  = t % HID;
        int kg = t / HID;
        int k  = kg * 8 + kr;
        D[i] = f2bf(S[(size_t)k * HID + n]);
    }
}

// ---------------- bf16 MFMA GEMM: A via LDS, B straight from L2 (packed) ----------------
// 64x320 blocks, 8 waves (2 row x 4 col). LDS only As (9.2KB) + sdred (4KB) -> high occupancy.
// z==0 (GAT): Cbf bf16 [M,320] + packed sd[row*16 +h]=s, [+8+h]=d from f32 accumulators.
// z==1 (proj): C2 = A@Bp2 + bias2 (f32).
#define QM  64
#define GKP 72   // padded LDS stride (144 B/row -> 2-way max, free)

template<int KK>
__global__ __launch_bounds__(512) void k_gemm4(
    const unsigned short* __restrict__ A,
    const unsigned short* __restrict__ Bp,
    unsigned short* __restrict__ Cbf,
    const float* __restrict__ a_s,
    const float* __restrict__ a_d,
    float* __restrict__ sd_out,
    const unsigned short* __restrict__ Bp2,
    const float* __restrict__ bias2,
    float* __restrict__ C2,
    int M)
{
    const bool gat = (blockIdx.z == 0);
    const unsigned short* __restrict__ B = gat ? Bp : Bp2;
    __shared__ unsigned short As[QM][GKP];
    __shared__ float sdred[4][2][QM][2];
    int tid = threadIdx.x;
    int lane = tid & 63, wid = tid >> 6;
    int wr = wid >> 2, wc = wid & 3;      // 2 (rows) x 4 (cols) wave grid
    int q = lane >> 4, r16 = lane & 15;
    int m0 = blockIdx.x * QM;

    // per-lane packed-B base: col = wc*80 + ni*16 + r16, k-group offset q already folded in
    const unsigned short* pB[5];
#pragma unroll
    for (int ni = 0; ni < 5; ++ni)
        pB[ni] = B + (size_t)(wc * 80 + ni * 16 + r16) * 8 + (size_t)q * (HID * 8);

    f32x4 acc[2][5];
#pragma unroll
    for (int mi = 0; mi < 2; ++mi)
#pragma unroll
        for (int ni = 0; ni < 5; ++ni)
#pragma unroll
            for (int r = 0; r < 4; ++r) acc[mi][ni][r] = 0.f;

    for (int k0 = 0; k0 < KK; k0 += 64) {
        {   // stage A tile 64x64: one bf16x8 per thread
            int m = tid >> 3, g = tid & 7;
            int row = m0 + m;
            bf16x8 v;
            if (row < M) v = *(const bf16x8*)(A + (size_t)row * KK + k0 + g * 8);
            else { for (int j = 0; j < 8; ++j) v[j] = 0; }
            *(bf16x8*)&As[m][g * 8] = v;
        }
        __syncthreads();
#pragma unroll
        for (int kc = 0; kc < 2; ++kc) {
            bf16x8 av[2], bv[5];
#pragma unroll
            for (int mi = 0; mi < 2; ++mi)
                av[mi] = *(const bf16x8*)&As[wr * 32 + mi * 16 + r16][kc * 32 + q * 8];
#pragma unroll
            for (int ni = 0; ni < 5; ++ni)
                bv[ni] = *(const bf16x8*)(pB[ni] + (size_t)k0 * HID + kc * (4 * HID * 8));
#pragma unroll
            for (int mi = 0; mi < 2; ++mi)
#pragma unroll
                for (int ni = 0; ni < 5; ++ni)
                    acc[mi][ni] = __builtin_amdgcn_mfma_f32_16x16x32_bf16(av[mi], bv[ni], acc[mi][ni], 0, 0, 0);
        }
        __syncthreads();
    }

    if (gat) {
#pragma unroll
        for (int mi = 0; mi < 2; ++mi)
#pragma unroll
            for (int ni = 0; ni < 5; ++ni) {
                int col = wc * 80 + ni * 16 + r16;
#pragma unroll
                for (int r = 0; r < 4; ++r) {
                    int row = m0 + wr * 32 + mi * 16 + q * 4 + r;
                    if (row < M) Cbf[(size_t)row * HID + col] = f2bf(acc[mi][ni][r]);
                }
            }
        // per-head s/d partials: each 16-wide frag lies in one head; wave covers 2 heads
        int headA = (5 * wc) >> 2;
#pragma unroll
        for (int mi = 0; mi < 2; ++mi)
#pragma unroll
            for (int r = 0; r < 4; ++r) {
                float psA = 0.f, pdA = 0.f, psB = 0.f, pdB = 0.f;
#pragma unroll
                for (int ni = 0; ni < 5; ++ni) {
                    int col = wc * 80 + ni * 16 + r16;
                    int hf = (5 * wc + ni) >> 2;
                    float v = acc[mi][ni][r];
                    float ps = v * a_s[col], pd = v * a_d[col];
                    if (hf == headA) { psA += ps; pdA += pd; }
                    else             { psB += ps; pdB += pd; }
                }
#pragma unroll
                for (int w = 8; w >= 1; w >>= 1) {
                    psA += __shfl_xor(psA, w, 64);
                    pdA += __shfl_xor(pdA, w, 64);
                    psB += __shfl_xor(psB, w, 64);
                    pdB += __shfl_xor(pdB, w, 64);
                }
                if (r16 == 0) {
                    int rl = wr * 32 + mi * 16 + q * 4 + r;
                    sdred[wc][0][rl][0] = psA; sdred[wc][0][rl][1] = pdA;
                    sdred[wc][1][rl][0] = psB; sdred[wc][1][rl][1] = pdB;
                }
            }
        __syncthreads();
        if (tid < QM) {
            int row = m0 + tid;
            if (row < M) {
                float s0 = sdred[0][0][tid][0];
                float s1 = sdred[0][1][tid][0] + sdred[1][0][tid][0];
                float s2 = sdred[1][1][tid][0] + sdred[2][0][tid][0];
                float s3 = sdred[2][1][tid][0] + sdred[3][0][tid][0];
                float s4 = sdred[3][1][tid][0];
                float d0 = sdred[0][0][tid][1];
                float d1 = sdred[0][1][tid][1] + sdred[1][0][tid][1];
                float d2 = sdred[1][1][tid][1] + sdred[2][0][tid][1];
                float d3 = sdred[2][1][tid][1] + sdred[3][0][tid][1];
                float d4 = sdred[3][1][tid][1];
                size_t sb = (size_t)row * 16;
                sd_out[sb + 0] = s0; sd_out[sb + 1] = s1; sd_out[sb + 2] = s2;
                sd_out[sb + 3] = s3; sd_out[sb + 4] = s4;
                sd_out[sb + 8] = d0; sd_out[sb + 9] = d1; sd_out[sb + 10] = d2;
                sd_out[sb + 11] = d3; sd_out[sb + 12] = d4;
            }
        }
    } else {
#pragma unroll
        for (int mi = 0; mi < 2; ++mi)
#pragma unroll
            for (int ni = 0; ni < 5; ++ni) {
                int col = wc * 80 + ni * 16 + r16;
                float bval = bias2[col];
#pragma unroll
                for (int r = 0; r < 4; ++r) {
                    int row = m0 + wr * 32 + mi * 16 + q * 4 + r;
                    if (row < M) C2[(size_t)row * HID + col] = acc[mi][ni][r] + bval;
                }
            }
    }
}

// ---------------- GAT aggregation: R7 (best measured) — packed LDS record broadcast ----------------
__global__ __launch_bounds__(256) void k_agg(const unsigned short* __restrict__ gatbf,
                                             const float* __restrict__ sd,
                                             const int* __restrict__ off, const int* __restrict__ srcl,
                                             const float* __restrict__ bias, const float* __restrict__ base,
                                             float* __restrict__ outp, unsigned short* __restrict__ out_bf) {
    __shared__ uint4 rec[4][64];
    int wid = threadIdx.x >> 6;
    int lane = threadIdx.x & 63;
    int i = blockIdx.x * 4 + wid;
    if (i >= N_NODES) return;
    int oS = off[i], oE = off[i + 1];
    int deg = oE - oS;
    const bool lo32 = (lane < 32);

    const float4 dv = *(const float4*)&sd[(size_t)i * 16 + 8];
    const float di4v = sd[(size_t)i * 16 + 12];
    float di[5] = {dv.x, dv.y, dv.z, dv.w, di4v};

    const unsigned short* pa = gatbf + 2 * lane;
    const unsigned short* pb = gatbf + 128 + 2 * lane;
    const unsigned short* pc = gatbf + 256 + lane;

    float m[5], den[5] = {0.f, 0.f, 0.f, 0.f, 0.f};
#pragma unroll
    for (int h = 0; h < 5; ++h) m[h] = -1e30f;
    float a0x = 0.f, a0y = 0.f, a1x = 0.f, a1y = 0.f, a2 = 0.f;

    for (int cb = 0; cb < deg; cb += 64) {
        int j = cb + lane;
        bool act = (j < deg);
        int sj = act ? srcl[oS + j] : 0;
        float e[5];
        if (act) {
            const float4 sv = *(const float4*)&sd[(size_t)sj * 16];
            float s4 = sd[(size_t)sj * 16 + 4];
            float es0 = sv.x + di[0], es1 = sv.y + di[1], es2 = sv.z + di[2];
            float es3 = sv.w + di[3], es4 = s4 + di[4];
            e[0] = (es0 >= 0.f) ? es0 : 0.2f * es0;
            e[1] = (es1 >= 0.f) ? es1 : 0.2f * es1;
            e[2] = (es2 >= 0.f) ? es2 : 0.2f * es2;
            e[3] = (es3 >= 0.f) ? es3 : 0.2f * es3;
            e[4] = (es4 >= 0.f) ? es4 : 0.2f * es4;
        } else {
#pragma unroll
            for (int h = 0; h < 5; ++h) e[h] = -1e30f;
        }
        float cm[5];
#pragma unroll
        for (int h = 0; h < 5; ++h) cm[h] = e[h];
#pragma unroll
        for (int w = 32; w >= 1; w >>= 1)
#pragma unroll
            for (int h = 0; h < 5; ++h) cm[h] = fmaxf(cm[h], __shfl_xor(cm[h], w, 64));
        if (cb) {  // online rescale (deg > 64) — practically never taken
            float r[5];
#pragma unroll
            for (int h = 0; h < 5; ++h) {
                float nm = fmaxf(m[h], cm[h]);
                r[h] = __expf(m[h] - nm);
                m[h] = nm;
                den[h] *= r[h];
            }
            float rA = lo32 ? r[0] : r[1], rB = lo32 ? r[2] : r[3];
            a0x *= rA; a0y *= rA; a1x *= rB; a1y *= rB; a2 *= r[4];
        } else {
#pragma unroll
            for (int h = 0; h < 5; ++h) m[h] = cm[h];
        }
        float ex[5];
#pragma unroll
        for (int h = 0; h < 5; ++h) {
            ex[h] = act ? __expf(e[h] - m[h]) : 0.f;
            den[h] += ex[h];
        }
        // pack {offset, w0..w4 bf16} into one 16B record (weights bf16: den stays f32)
        uint4 rk;
        rk.x = (unsigned)(sj * HID);
        rk.y = (unsigned)f2bf(ex[0]) | ((unsigned)f2bf(ex[1]) << 16);
        rk.z = (unsigned)f2bf(ex[2]) | ((unsigned)f2bf(ex[3]) << 16);
        rk.w = (unsigned)f2bf(ex[4]);
        rec[wid][lane] = rk;
        int cnt = min(64, deg - cb);
        for (int jj = 0; jj < cnt; ++jj) {
            uint4 r = rec[wid][jj];          // uniform address -> LDS broadcast
            int o = (int)r.x;
            float wA = bf2f((unsigned short)(lo32 ? (r.y & 0xffffu) : (r.y >> 16)));
            float wB = bf2f((unsigned short)(lo32 ? (r.z & 0xffffu) : (r.z >> 16)));
            float w4v = bf2f((unsigned short)r.w);
            u16x2 p0 = *(const u16x2*)(pa + o);
            u16x2 p1 = *(const u16x2*)(pb + o);
            unsigned short p2v = pc[o];
            a0x += wA * bf2f(p0[0]);
            a0y += wA * bf2f(p0[1]);
            a1x += wB * bf2f(p1[0]);
            a1y += wB * bf2f(p1[1]);
            a2  += w4v * bf2f(p2v);
        }
    }
#pragma unroll
    for (int w = 32; w >= 1; w >>= 1)
#pragma unroll
        for (int h = 0; h < 5; ++h) den[h] += __shfl_xor(den[h], w, 64);

    float dA = lo32 ? den[0] : den[1], dB = lo32 ? den[2] : den[3];
    int c0i = 2 * lane, c1i = 128 + 2 * lane, c2i = 256 + lane;
    size_t rb = (size_t)i * HID;
    float2 bi0 = *(const float2*)&bias[c0i];
    float2 bi1 = *(const float2*)&bias[c1i];
    float  bi2 = bias[c2i];
    float2 ba0 = *(const float2*)&base[rb + c0i];
    float2 ba1 = *(const float2*)&base[rb + c1i];
    float  ba2 = base[rb + c2i];
    float2 o0v, o1v;
    o0v.x = ba0.x + fmaxf(a0x / dA + bi0.x, 0.f);
    o0v.y = ba0.y + fmaxf(a0y / dA + bi0.y, 0.f);
    o1v.x = ba1.x + fmaxf(a1x / dB + bi1.x, 0.f);
    o1v.y = ba1.y + fmaxf(a1y / dB + bi1.y, 0.f);
    float o2v = ba2 + fmaxf(a2 / den[4] + bi2, 0.f);
    *(float2*)&outp[rb + c0i] = o0v;
    *(float2*)&outp[rb + c1i] = o1v;
    outp[rb + c2i] = o2v;
    if (out_bf) {
        u16x2 q0, q1;
        q0[0] = f2bf(o0v.x); q0[1] = f2bf(o0v.y);
        q1[0] = f2bf(o1v.x); q1[1] = f2bf(o1v.y);
        *(u16x2*)&out_bf[rb + c0i] = q0;
        *(u16x2*)&out_bf[rb + c1i] = q1;
        out_bf[rb + c2i] = f2bf(o2v);
    }
}

// ---------------- pooling: segment mean over sorted batch (200x5 blocks) ----------------
__global__ __launch_bounds__(64) void k_pool(const float* __restrict__ h, const int* __restrict__ batch,
                                             float* __restrict__ pooled) {
    int g = blockIdx.x;
    int t = blockIdx.y * 64 + threadIdx.x;  // col 0..319
    int lo = 0, hi = N_NODES;
    while (lo < hi) { int mid = (lo + hi) >> 1; if (batch[mid] < g) lo = mid + 1; else hi = mid; }
    int start = lo;
    hi = N_NODES;
    while (lo < hi) { int mid = (lo + hi) >> 1; if (batch[mid] < g + 1) lo = mid + 1; else hi = mid; }
    int end = lo;
    float acc = 0.f;
    for (int r = start; r < end; ++r) acc += h[(size_t)r * HID + t];
    float cntf = (float)(end - start);
    pooled[g * HID + t] = acc / fmaxf(cntf, 1.f);
}

// ---------------- MLP head ----------------
__global__ __launch_bounds__(64) void k_mlp1(const float* __restrict__ pooled, const float* __restrict__ W,
                                             const float* __restrict__ b, float* __restrict__ z1) {
    int r = blockIdx.x;
    int col = blockIdx.y * 64 + threadIdx.x;
    float acc = 0.f;
    for (int k = 0; k < HID; ++k) acc += pooled[r * HID + k] * W[k * NHID + col];
    acc += b[col];
    z1[r * NHID + col] = fmaxf(acc, 0.f);
}

__global__ __launch_bounds__(256) void k_mlp2_ln(const float* __restrict__ z1, const float* __restrict__ W,
                                                 const float* __restrict__ b, const float* __restrict__ g_,
                                                 const float* __restrict__ beta, float* __restrict__ outp) {
    int r = blockIdx.x;
    int col = threadIdx.x;  // 256
    float acc = 0.f;
    for (int k = 0; k < NHID; ++k) acc += z1[r * NHID + k] * W[k * NOUT + col];
    acc += b[col];
    __shared__ float red[256];
    red[col] = acc;
    __syncthreads();
    for (int s = 128; s > 0; s >>= 1) { if (col < s) red[col] += red[col + s]; __syncthreads(); }
    float mu = red[0] / (float)NOUT;
    __syncthreads();
    float dv = acc - mu;
    red[col] = dv * dv;
    __syncthreads();
    for (int s = 128; s > 0; s >>= 1) { if (col < s) red[col] += red[col + s]; __syncthreads(); }
    float var = red[0] / (float)NOUT;
    outp[r * NOUT + col] = g_[col] * dv * rsqrtf(var + 1e-5f) + beta[col];
}

// ---------------- launch ----------------
extern "C" void kernel_launch(void* const* d_in, const int* in_sizes, int n_in,
                              void* d_out, int out_size, void* d_ws, size_t ws_size,
                              hipStream_t stream) {
    const float* x     = (const float*)d_in[0];
    const int*   ei    = (const int*)d_in[1];
    const int*   batch = (const int*)d_in[2];
    const float *W[5], *as_[5], *ad_[5], *bb[5];
    int idx = 3;
    for (int l = 0; l < 5; ++l) {
        W[l]   = (const float*)d_in[idx++];
        as_[l] = (const float*)d_in[idx++];
        ad_[l] = (const float*)d_in[idx++];
        bb[l]  = (const float*)d_in[idx++];
    }
    const float* Wm1 = (const float*)d_in[idx++];
    const float* bm1 = (const float*)d_in[idx++];
    const float* Wm2 = (const float*)d_in[idx++];
    const float* bm2 = (const float*)d_in[idx++];
    const float* Wh1 = (const float*)d_in[idx++];
    const float* bh1 = (const float*)d_in[idx++];
    const float* Wh2 = (const float*)d_in[idx++];
    const float* bh2 = (const float*)d_in[idx++];
    const float* lng = (const float*)d_in[idx++];
    const float* lnb = (const float*)d_in[idx++];

    const int E = in_sizes[1] / 2;
    float* out = (float*)d_out;

    char* ws = (char*)d_ws;
    size_t o = 0;
    auto alloc = [&](size_t bytes) -> char* {
        char* p = ws + o;
        o += bytes;
        o = (o + 255) & ~(size_t)255;
        return p;
    };
    const size_t NB = (size_t)N_NODES * HID * sizeof(float);
    float* big1   = (float*)alloc(NB);
    float* big2   = (float*)alloc(NB);
    float* sdbuf  = (float*)alloc((size_t)N_NODES * 16 * sizeof(float));
    int*   cnt    = (int*)alloc((size_t)N_NODES * sizeof(int));
    int*   off    = (int*)alloc((size_t)(N_NODES + 1) * sizeof(int));
    int*   cur    = (int*)alloc((size_t)N_NODES * sizeof(int));
    int*   srcl   = (int*)alloc((size_t)(E + N_NODES) * sizeof(int));
    float* pooled = (float*)alloc((size_t)G_GRAPHS * HID * sizeof(float));
    float* z1     = (float*)alloc((size_t)G_GRAPHS * NHID * sizeof(float));
    unsigned short* x_bf   = (unsigned short*)alloc((size_t)N_NODES * F_IN * sizeof(short));
    unsigned short* h_bf   = (unsigned short*)alloc((size_t)N_NODES * HID * sizeof(short));
    unsigned short* gat_bf = (unsigned short*)alloc((size_t)N_NODES * HID * sizeof(short));
    unsigned short* Wt1  = (unsigned short*)alloc((size_t)HID * F_IN * sizeof(short));
    unsigned short* Wtm1 = (unsigned short*)alloc((size_t)HID * F_IN * sizeof(short));
    unsigned short* Wt2  = (unsigned short*)alloc((size_t)HID * HID * sizeof(short));
    unsigned short* Wtm2 = (unsigned short*)alloc((size_t)HID * HID * sizeof(short));
    unsigned short* Wt3  = (unsigned short*)alloc((size_t)HID * HID * sizeof(short));
    unsigned short* Wt4  = (unsigned short*)alloc((size_t)HID * HID * sizeof(short));
    unsigned short* Wt5  = (unsigned short*)alloc((size_t)HID * HID * sizeof(short));

    // CSR (4 launches)
    k_init_cnt<<<(N_NODES + 255) / 256, 256, 0, stream>>>(cnt);
    k_hist<<<(E + 255) / 256, 256, 0, stream>>>(ei, cnt, E);
    k_scan<<<1, 1024, 0, stream>>>(cnt, off, cur);
    k_fill<<<(N_NODES + E + 255) / 256, 256, 0, stream>>>(ei, cur, srcl, E);

    // conversions (2 launches)
    {
        int n = N_NODES * F_IN;
        k_cvt<<<(n + 255) / 256, 256, 0, stream>>>(x, x_bf, n);
        dim3 wt_grid((HID * HID + 255) / 256, 7);
        k_wt_all<<<wt_grid, 256, 0, stream>>>(W[0], Wm1, W[1], Wm2, W[2], W[3], W[4],
                                              Wt1, Wtm1, Wt2, Wtm2, Wt3, Wt4, Wt5);
    }

    const int MB = (N_NODES + QM - 1) / QM;  // 313
    dim3 gg2(MB, 1, 2);
    dim3 gg1(MB, 1, 1);
    const int AGG_B = (N_NODES + 3) / 4;

    // Layer 1
    k_gemm4<F_IN><<<gg2, 512, 0, stream>>>(x_bf, Wt1, gat_bf, as_[0], ad_[0], sdbuf,
                                           Wtm1, bm1, big1, N_NODES);
    k_agg<<<AGG_B, 256, 0, stream>>>(gat_bf, sdbuf, off, srcl, bb[0], big1, big1, h_bf);

    // Layer 2
    k_gemm4<HID><<<gg2, 512, 0, stream>>>(h_bf, Wt2, gat_bf, as_[1], ad_[1], sdbuf,
                                          Wtm2, bm2, big2, N_NODES);
    k_agg<<<AGG_B, 256, 0, stream>>>(gat_bf, sdbuf, off, srcl, bb[1], big2, big2, h_bf);

    // Layers 3-5: h = h + relu(gat(h)) in place on big2
    const unsigned short* Wtl[3] = {Wt3, Wt4, Wt5};
    for (int l = 2; l < 5; ++l) {
        k_gemm4<HID><<<gg1, 512, 0, stream>>>(h_bf, Wtl[l - 2], gat_bf, as_[l], ad_[l], sdbuf,
                                              nullptr, nullptr, nullptr, N_NODES);
        unsigned short* mirror = (l < 4) ? h_bf : nullptr;
        k_agg<<<AGG_B, 256, 0, stream>>>(gat_bf, sdbuf, off, srcl, bb[l], big2, big2, mirror);
    }

    // pool + head
    k_pool<<<dim3(G_GRAPHS, HID / 64), 64, 0, stream>>>(big2, batch, pooled);
    k_mlp1<<<dim3(G_GRAPHS, NHID / 64), 64, 0, stream>>>(pooled, Wh1, bh1, z1);
    k_mlp2_ln<<<G_GRAPHS, NOUT, 0, stream>>>(z1, Wh2, bh2, lng, lnb, out);
}

// Round 10
// 479.663 us; speedup vs baseline: 1.0097x; 1.0097x over previous
//
#include <hip/hip_runtime.h>
#include <math.h>

#define N_NODES 20000
#define F_IN    128
#define H_HEADS 5
#define HID     320
#define NHID    512
#define NOUT    256
#define G_GRAPHS 200

typedef __attribute__((ext_vector_type(8))) short bf16x8;
typedef __attribute__((ext_vector_type(4))) float f32x4;
typedef __attribute__((ext_vector_type(2))) unsigned short u16x2;
typedef __attribute__((ext_vector_type(4))) unsigned short u16x4;

__device__ __forceinline__ unsigned short f2bf(float f) {
    unsigned int u = __float_as_uint(f);
    u += 0x7fffu + ((u >> 16) & 1u);
    return (unsigned short)(u >> 16);
}
__device__ __forceinline__ float bf2f(unsigned short u) {
    return __uint_as_float(((unsigned int)u) << 16);
}

// ---------------- CSR build (dst -> list of src), self-loops included ----------------
__global__ void k_init_cnt(int* cnt) {
    int i = blockIdx.x * 256 + threadIdx.x;
    if (i < N_NODES) cnt[i] = 1;  // self loop
}

__global__ void k_hist(const int* __restrict__ ei, int* cnt, int E) {
    int e = blockIdx.x * 256 + threadIdx.x;
    if (e < E) atomicAdd(&cnt[ei[E + e]], 1);
}

__global__ __launch_bounds__(1024) void k_scan(const int* __restrict__ cnt, int* off, int* cur) {
    __shared__ int part[1024];
    int t = threadIdx.x;
    const int per = (N_NODES + 1023) / 1024;
    int base = t * per;
    int sum = 0;
    for (int i = 0; i < per; ++i) { int idx = base + i; if (idx < N_NODES) sum += cnt[idx]; }
    part[t] = sum;
    __syncthreads();
    for (int s = 1; s < 1024; s <<= 1) {
        int v = (t >= s) ? part[t - s] : 0;
        __syncthreads();
        part[t] += v;
        __syncthreads();
    }
    int run = (t == 0) ? 0 : part[t - 1];
    for (int i = 0; i < per; ++i) {
        int idx = base + i;
        if (idx < N_NODES) { off[idx] = run; cur[idx] = run; run += cnt[idx]; }
    }
    if (t == 1023) off[N_NODES] = part[1023];
}

// merged self-loop + edge fill
__global__ void k_fill(const int* __restrict__ ei, int* cur, int* srcl, int E) {
    int idx = blockIdx.x * 256 + threadIdx.x;
    if (idx < N_NODES) {
        int p = atomicAdd(&cur[idx], 1);
        srcl[p] = idx;
    } else {
        int e = idx - N_NODES;
        if (e < E) {
            int d = ei[E + e];
            int p = atomicAdd(&cur[d], 1);
            srcl[p] = ei[e];
        }
    }
}

// ---------------- conversions ----------------
__global__ void k_cvt(const float* __restrict__ in, unsigned short* __restrict__ outp, int n) {
    int i = blockIdx.x * 256 + threadIdx.x;
    if (i < n) outp[i] = f2bf(in[i]);
}

// all 7 weight packs in one launch: W [K,320] f32 -> Bp [K/8][320][8] bf16
__global__ void k_wt_all(const float* __restrict__ s0, const float* __restrict__ s1,
                         const float* __restrict__ s2, const float* __restrict__ s3,
                         const float* __restrict__ s4, const float* __restrict__ s5,
                         const float* __restrict__ s6,
                         unsigned short* __restrict__ d0, unsigned short* __restrict__ d1,
                         unsigned short* __restrict__ d2, unsigned short* __restrict__ d3,
                         unsigned short* __restrict__ d4, unsigned short* __restrict__ d5,
                         unsigned short* __restrict__ d6) {
    int y = blockIdx.y;
    const float* S; unsigned short* D; int K;
    switch (y) {
        case 0: S = s0; D = d0; K = F_IN; break;
        case 1: S = s1; D = d1; K = F_IN; break;
        case 2: S = s2; D = d2; K = HID; break;
        case 3: S = s3; D = d3; K = HID; break;
        case 4: S = s4; D = d4; K = HID; break;
        case 5: S = s5; D = d5; K = HID; break;
        default: S = s6; D = d6; K = HID; break;
    }
    int n_elems = HID * K;
    int i = blockIdx.x * 256 + threadIdx.x;
    if (i < n_elems) {
        int kr = i & 7;
        int t  = i >> 3;          // kg*320 + n
        int n  = t % HID;
        int kg = t / HID;
        int k  = kg * 8 + kr;
        D[i] = f2bf(S[(size_t)k * HID + n]);
    }
}

// ---------------- bf16 MFMA GEMM: QM=32, 256 threads, 4 waves (grid 625/z) ----------------
// Each wave: 32 rows x 80 cols = 2x5 frags (same shape as R8; only the block got smaller).
// A via LDS (4.6KB); B straight from L2 (packed [K/8][320][8]).
// z==0 (GAT): Cbf bf16 + packed sd. z==1 (proj): C2 = A@Bp2 + bias2.
#define QM  32
#define GKP 72

template<int KK>
__global__ __launch_bounds__(256) void k_gemm5(
    const unsigned short* __restrict__ A,
    const unsigned short* __restrict__ Bp,
    unsigned short* __restrict__ Cbf,
    const float* __restrict__ a_s,
    const float* __restrict__ a_d,
    float* __restrict__ sd_out,
    const unsigned short* __restrict__ Bp2,
    const float* __restrict__ bias2,
    float* __restrict__ C2,
    int M)
{
    const bool gat = (blockIdx.z == 0);
    const unsigned short* __restrict__ B = gat ? Bp : Bp2;
    __shared__ unsigned short As[QM][GKP];
    __shared__ float sdred[4][2][QM][2];
    int tid = threadIdx.x;
    int lane = tid & 63, wid = tid >> 6;
    int wc = wid;                          // 4 col-waves, 80 cols each; all rows
    int q = lane >> 4, r16 = lane & 15;
    int m0 = blockIdx.x * QM;

    const unsigned short* pB[5];
#pragma unroll
    for (int ni = 0; ni < 5; ++ni)
        pB[ni] = B + (size_t)(wc * 80 + ni * 16 + r16) * 8 + (size_t)q * (HID * 8);

    f32x4 acc[2][5];
#pragma unroll
    for (int mi = 0; mi < 2; ++mi)
#pragma unroll
        for (int ni = 0; ni < 5; ++ni)
#pragma unroll
            for (int r = 0; r < 4; ++r) acc[mi][ni][r] = 0.f;

    for (int k0 = 0; k0 < KK; k0 += 64) {
        {   // stage A tile 32x64: one bf16x8 per thread
            int m = tid >> 3, g = tid & 7;
            int row = m0 + m;
            bf16x8 v;
            if (row < M) v = *(const bf16x8*)(A + (size_t)row * KK + k0 + g * 8);
            else { for (int j = 0; j < 8; ++j) v[j] = 0; }
            *(bf16x8*)&As[m][g * 8] = v;
        }
        __syncthreads();
#pragma unroll
        for (int kc = 0; kc < 2; ++kc) {
            bf16x8 av[2], bv[5];
#pragma unroll
            for (int mi = 0; mi < 2; ++mi)
                av[mi] = *(const bf16x8*)&As[mi * 16 + r16][kc * 32 + q * 8];
#pragma unroll
            for (int ni = 0; ni < 5; ++ni)
                bv[ni] = *(const bf16x8*)(pB[ni] + (size_t)k0 * HID + kc * (4 * HID * 8));
#pragma unroll
            for (int mi = 0; mi < 2; ++mi)
#pragma unroll
                for (int ni = 0; ni < 5; ++ni)
                    acc[mi][ni] = __builtin_amdgcn_mfma_f32_16x16x32_bf16(av[mi], bv[ni], acc[mi][ni], 0, 0, 0);
        }
        __syncthreads();
    }

    if (gat) {
#pragma unroll
        for (int mi = 0; mi < 2; ++mi)
#pragma unroll
            for (int ni = 0; ni < 5; ++ni) {
                int col = wc * 80 + ni * 16 + r16;
#pragma unroll
                for (int r = 0; r < 4; ++r) {
                    int row = m0 + mi * 16 + q * 4 + r;
                    if (row < M) Cbf[(size_t)row * HID + col] = f2bf(acc[mi][ni][r]);
                }
            }
        int headA = (5 * wc) >> 2;
#pragma unroll
        for (int mi = 0; mi < 2; ++mi)
#pragma unroll
            for (int r = 0; r < 4; ++r) {
                float psA = 0.f, pdA = 0.f, psB = 0.f, pdB = 0.f;
#pragma unroll
                for (int ni = 0; ni < 5; ++ni) {
                    int col = wc * 80 + ni * 16 + r16;
                    int hf = (5 * wc + ni) >> 2;
                    float v = acc[mi][ni][r];
                    float ps = v * a_s[col], pd = v * a_d[col];
                    if (hf == headA) { psA += ps; pdA += pd; }
                    else             { psB += ps; pdB += pd; }
                }
#pragma unroll
                for (int w = 8; w >= 1; w >>= 1) {
                    psA += __shfl_xor(psA, w, 64);
                    pdA += __shfl_xor(pdA, w, 64);
                    psB += __shfl_xor(psB, w, 64);
                    pdB += __shfl_xor(pdB, w, 64);
                }
                if (r16 == 0) {
                    int rl = mi * 16 + q * 4 + r;
                    sdred[wc][0][rl][0] = psA; sdred[wc][0][rl][1] = pdA;
                    sdred[wc][1][rl][0] = psB; sdred[wc][1][rl][1] = pdB;
                }
            }
        __syncthreads();
        if (tid < QM) {
            int row = m0 + tid;
            if (row < M) {
                float s0 = sdred[0][0][tid][0];
                float s1 = sdred[0][1][tid][0] + sdred[1][0][tid][0];
                float s2 = sdred[1][1][tid][0] + sdred[2][0][tid][0];
                float s3 = sdred[2][1][tid][0] + sdred[3][0][tid][0];
                float s4 = sdred[3][1][tid][0];
                float d0 = sdred[0][0][tid][1];
                float d1 = sdred[0][1][tid][1] + sdred[1][0][tid][1];
                float d2 = sdred[1][1][tid][1] + sdred[2][0][tid][1];
                float d3 = sdred[2][1][tid][1] + sdred[3][0][tid][1];
                float d4 = sdred[3][1][tid][1];
                size_t sb = (size_t)row * 16;
                sd_out[sb + 0] = s0; sd_out[sb + 1] = s1; sd_out[sb + 2] = s2;
                sd_out[sb + 3] = s3; sd_out[sb + 4] = s4;
                sd_out[sb + 8] = d0; sd_out[sb + 9] = d1; sd_out[sb + 10] = d2;
                sd_out[sb + 11] = d3; sd_out[sb + 12] = d4;
            }
        }
    } else {
#pragma unroll
        for (int mi = 0; mi < 2; ++mi)
#pragma unroll
            for (int ni = 0; ni < 5; ++ni) {
                int col = wc * 80 + ni * 16 + r16;
                float bval = bias2[col];
#pragma unroll
                for (int r = 0; r < 4; ++r) {
                    int row = m0 + mi * 16 + q * 4 + r;
                    if (row < M) C2[(size_t)row * HID + col] = acc[mi][ni][r] + bval;
                }
            }
    }
}

// ---------------- GAT aggregation: packed LDS record broadcast, 4+1 column split ----------------
// 4 waves/block, one node per wave; lane covers cols {4l..4l+3} (8B load) + {256+l} (2B).
// Per edge: 1 uniform ds_read_b128 + 2 global loads + 5 fma. No barriers.
__global__ __launch_bounds__(256) void k_agg(const unsigned short* __restrict__ gatbf,
                                             const float* __restrict__ sd,
                                             const int* __restrict__ off, const int* __restrict__ srcl,
                                             const float* __restrict__ bias, const float* __restrict__ base,
                                             float* __restrict__ outp, unsigned short* __restrict__ out_bf) {
    __shared__ uint4 rec[4][64];
    int wid = threadIdx.x >> 6;
    int lane = threadIdx.x & 63;
    int i = blockIdx.x * 4 + wid;
    if (i >= N_NODES) return;
    int oS = off[i], oE = off[i + 1];
    int deg = oE - oS;
    const int hsel = lane >> 4;   // which head owns cols 4l..4l+3 (0..3)
    const bool lo32 = (lane < 32);

    const float4 dv = *(const float4*)&sd[(size_t)i * 16 + 8];
    const float di4v = sd[(size_t)i * 16 + 12];
    float di[5] = {dv.x, dv.y, dv.z, dv.w, di4v};

    const unsigned short* pa = gatbf + 4 * lane;        // cols 4l..4l+3
    const unsigned short* pc = gatbf + 256 + lane;      // col 256+l

    float m[5], den[5] = {0.f, 0.f, 0.f, 0.f, 0.f};
#pragma unroll
    for (int h = 0; h < 5; ++h) m[h] = -1e30f;
    float a0 = 0.f, a1 = 0.f, a2 = 0.f, a3 = 0.f, a4 = 0.f;

    for (int cb = 0; cb < deg; cb += 64) {
        int j = cb + lane;
        bool act = (j < deg);
        int sj = act ? srcl[oS + j] : 0;
        float e[5];
        if (act) {
            const float4 sv = *(const float4*)&sd[(size_t)sj * 16];
            float s4 = sd[(size_t)sj * 16 + 4];
            float es0 = sv.x + di[0], es1 = sv.y + di[1], es2 = sv.z + di[2];
            float es3 = sv.w + di[3], es4 = s4 + di[4];
            e[0] = (es0 >= 0.f) ? es0 : 0.2f * es0;
            e[1] = (es1 >= 0.f) ? es1 : 0.2f * es1;
            e[2] = (es2 >= 0.f) ? es2 : 0.2f * es2;
            e[3] = (es3 >= 0.f) ? es3 : 0.2f * es3;
            e[4] = (es4 >= 0.f) ? es4 : 0.2f * es4;
        } else {
#pragma unroll
            for (int h = 0; h < 5; ++h) e[h] = -1e30f;
        }
        float cm[5];
#pragma unroll
        for (int h = 0; h < 5; ++h) cm[h] = e[h];
#pragma unroll
        for (int w = 32; w >= 1; w >>= 1)
#pragma unroll
            for (int h = 0; h < 5; ++h) cm[h] = fmaxf(cm[h], __shfl_xor(cm[h], w, 64));
        if (cb) {  // online rescale (deg > 64) — practically never taken
            float r[5];
#pragma unroll
            for (int h = 0; h < 5; ++h) {
                float nm = fmaxf(m[h], cm[h]);
                r[h] = __expf(m[h] - nm);
                m[h] = nm;
                den[h] *= r[h];
            }
            float rA = (hsel == 0) ? r[0] : (hsel == 1) ? r[1] : (hsel == 2) ? r[2] : r[3];
            a0 *= rA; a1 *= rA; a2 *= rA; a3 *= rA; a4 *= r[4];
        } else {
#pragma unroll
            for (int h = 0; h < 5; ++h) m[h] = cm[h];
        }
        float ex[5];
#pragma unroll
        for (int h = 0; h < 5; ++h) {
            ex[h] = act ? __expf(e[h] - m[h]) : 0.f;
            den[h] += ex[h];
        }
        uint4 rk;
        rk.x = (unsigned)(sj * HID);
        rk.y = (unsigned)f2bf(ex[0]) | ((unsigned)f2bf(ex[1]) << 16);
        rk.z = (unsigned)f2bf(ex[2]) | ((unsigned)f2bf(ex[3]) << 16);
        rk.w = (unsigned)f2bf(ex[4]);
        rec[wid][lane] = rk;
        int cnt = min(64, deg - cb);
        for (int jj = 0; jj < cnt; ++jj) {
            uint4 r = rec[wid][jj];          // uniform address -> LDS broadcast
            int o = (int)r.x;
            unsigned wlo = lo32 ? r.y : r.z;
            float wE = bf2f((unsigned short)((hsel & 1) ? (wlo >> 16) : (wlo & 0xffffu)));
            float w4v = bf2f((unsigned short)r.w);
            u16x4 p0 = *(const u16x4*)(pa + o);
            unsigned short p2v = pc[o];
            a0 += wE * bf2f(p0[0]);
            a1 += wE * bf2f(p0[1]);
            a2 += wE * bf2f(p0[2]);
            a3 += wE * bf2f(p0[3]);
            a4 += w4v * bf2f(p2v);
        }
    }
#pragma unroll
    for (int w = 32; w >= 1; w >>= 1)
#pragma unroll
        for (int h = 0; h < 5; ++h) den[h] += __shfl_xor(den[h], w, 64);

    float dE = (hsel == 0) ? den[0] : (hsel == 1) ? den[1] : (hsel == 2) ? den[2] : den[3];
    int c0i = 4 * lane, c2i = 256 + lane;
    size_t rb = (size_t)i * HID;
    float4 bi0 = *(const float4*)&bias[c0i];
    float  bi2 = bias[c2i];
    float4 ba0 = *(const float4*)&base[rb + c0i];
    float  ba2 = base[rb + c2i];
    float4 o0v;
    o0v.x = ba0.x + fmaxf(a0 / dE + bi0.x, 0.f);
    o0v.y = ba0.y + fmaxf(a1 / dE + bi0.y, 0.f);
    o0v.z = ba0.z + fmaxf(a2 / dE + bi0.z, 0.f);
    o0v.w = ba0.w + fmaxf(a3 / dE + bi0.w, 0.f);
    float o2v = ba2 + fmaxf(a4 / den[4] + bi2, 0.f);
    *(float4*)&outp[rb + c0i] = o0v;
    outp[rb + c2i] = o2v;
    if (out_bf) {
        u16x4 q0;
        q0[0] = f2bf(o0v.x); q0[1] = f2bf(o0v.y);
        q0[2] = f2bf(o0v.z); q0[3] = f2bf(o0v.w);
        *(u16x4*)&out_bf[rb + c0i] = q0;
        out_bf[rb + c2i] = f2bf(o2v);
    }
}

// ---------------- pooling: segment mean over sorted batch (200x5 blocks) ----------------
__global__ __launch_bounds__(64) void k_pool(const float* __restrict__ h, const int* __restrict__ batch,
                                             float* __restrict__ pooled) {
    int g = blockIdx.x;
    int t = blockIdx.y * 64 + threadIdx.x;  // col 0..319
    int lo = 0, hi = N_NODES;
    while (lo < hi) { int mid = (lo + hi) >> 1; if (batch[mid] < g) lo = mid + 1; else hi = mid; }
    int start = lo;
    hi = N_NODES;
    while (lo < hi) { int mid = (lo + hi) >> 1; if (batch[mid] < g + 1) lo = mid + 1; else hi = mid; }
    int end = lo;
    float acc = 0.f;
    for (int r = start; r < end; ++r) acc += h[(size_t)r * HID + t];
    float cntf = (float)(end - start);
    pooled[g * HID + t] = acc / fmaxf(cntf, 1.f);
}

// ---------------- MLP head ----------------
__global__ __launch_bounds__(64) void k_mlp1(const float* __restrict__ pooled, const float* __restrict__ W,
                                             const float* __restrict__ b, float* __restrict__ z1) {
    int r = blockIdx.x;
    int col = blockIdx.y * 64 + threadIdx.x;
    float acc = 0.f;
    for (int k = 0; k < HID; ++k) acc += pooled[r * HID + k] * W[k * NHID + col];
    acc += b[col];
    z1[r * NHID + col] = fmaxf(acc, 0.f);
}

__global__ __launch_bounds__(256) void k_mlp2_ln(const float* __restrict__ z1, const float* __restrict__ W,
                                                 const float* __restrict__ b, const float* __restrict__ g_,
                                                 const float* __restrict__ beta, float* __restrict__ outp) {
    int r = blockIdx.x;
    int col = threadIdx.x;  // 256
    float acc = 0.f;
    for (int k = 0; k < NHID; ++k) acc += z1[r * NHID + k] * W[k * NOUT + col];
    acc += b[col];
    __shared__ float red[256];
    red[col] = acc;
    __syncthreads();
    for (int s = 128; s > 0; s >>= 1) { if (col < s) red[col] += red[col + s]; __syncthreads(); }
    float mu = red[0] / (float)NOUT;
    __syncthreads();
    float dv = acc - mu;
    red[col] = dv * dv;
    __syncthreads();
    for (int s = 128; s > 0; s >>= 1) { if (col < s) red[col] += red[col + s]; __syncthreads(); }
    float var = red[0] / (float)NOUT;
    outp[r * NOUT + col] = g_[col] * dv * rsqrtf(var + 1e-5f) + beta[col];
}

// ---------------- launch ----------------
extern "C" void kernel_launch(void* const* d_in, const int* in_sizes, int n_in,
                              void* d_out, int out_size, void* d_ws, size_t ws_size,
                              hipStream_t stream) {
    const float* x     = (const float*)d_in[0];
    const int*   ei    = (const int*)d_in[1];
    const int*   batch = (const int*)d_in[2];
    const float *W[5], *as_[5], *ad_[5], *bb[5];
    int idx = 3;
    for (int l = 0; l < 5; ++l) {
        W[l]   = (const float*)d_in[idx++];
        as_[l] = (const float*)d_in[idx++];
        ad_[l] = (const float*)d_in[idx++];
        bb[l]  = (const float*)d_in[idx++];
    }
    const float* Wm1 = (const float*)d_in[idx++];
    const float* bm1 = (const float*)d_in[idx++];
    const float* Wm2 = (const float*)d_in[idx++];
    const float* bm2 = (const float*)d_in[idx++];
    const float* Wh1 = (const float*)d_in[idx++];
    const float* bh1 = (const float*)d_in[idx++];
    const float* Wh2 = (const float*)d_in[idx++];
    const float* bh2 = (const float*)d_in[idx++];
    const float* lng = (const float*)d_in[idx++];
    const float* lnb = (const float*)d_in[idx++];

    const int E = in_sizes[1] / 2;
    float* out = (float*)d_out;

    char* ws = (char*)d_ws;
    size_t o = 0;
    auto alloc = [&](size_t bytes) -> char* {
        char* p = ws + o;
        o += bytes;
        o = (o + 255) & ~(size_t)255;
        return p;
    };
    const size_t NB = (size_t)N_NODES * HID * sizeof(float);
    float* big1   = (float*)alloc(NB);
    float* big2   = (float*)alloc(NB);
    float* sdbuf  = (float*)alloc((size_t)N_NODES * 16 * sizeof(float));
    int*   cnt    = (int*)alloc((size_t)N_NODES * sizeof(int));
    int*   off    = (int*)alloc((size_t)(N_NODES + 1) * sizeof(int));
    int*   cur    = (int*)alloc((size_t)N_NODES * sizeof(int));
    int*   srcl   = (int*)alloc((size_t)(E + N_NODES) * sizeof(int));
    float* pooled = (float*)alloc((size_t)G_GRAPHS * HID * sizeof(float));
    float* z1     = (float*)alloc((size_t)G_GRAPHS * NHID * sizeof(float));
    unsigned short* x_bf   = (unsigned short*)alloc((size_t)N_NODES * F_IN * sizeof(short));
    unsigned short* h_bf   = (unsigned short*)alloc((size_t)N_NODES * HID * sizeof(short));
    unsigned short* gat_bf = (unsigned short*)alloc((size_t)N_NODES * HID * sizeof(short));
    unsigned short* Wt1  = (unsigned short*)alloc((size_t)HID * F_IN * sizeof(short));
    unsigned short* Wtm1 = (unsigned short*)alloc((size_t)HID * F_IN * sizeof(short));
    unsigned short* Wt2  = (unsigned short*)alloc((size_t)HID * HID * sizeof(short));
    unsigned short* Wtm2 = (unsigned short*)alloc((size_t)HID * HID * sizeof(short));
    unsigned short* Wt3  = (unsigned short*)alloc((size_t)HID * HID * sizeof(short));
    unsigned short* Wt4  = (unsigned short*)alloc((size_t)HID * HID * sizeof(short));
    unsigned short* Wt5  = (unsigned short*)alloc((size_t)HID * HID * sizeof(short));

    // CSR (4 launches)
    k_init_cnt<<<(N_NODES + 255) / 256, 256, 0, stream>>>(cnt);
    k_hist<<<(E + 255) / 256, 256, 0, stream>>>(ei, cnt, E);
    k_scan<<<1, 1024, 0, stream>>>(cnt, off, cur);
    k_fill<<<(N_NODES + E + 255) / 256, 256, 0, stream>>>(ei, cur, srcl, E);

    // conversions (2 launches)
    {
        int n = N_NODES * F_IN;
        k_cvt<<<(n + 255) / 256, 256, 0, stream>>>(x, x_bf, n);
        dim3 wt_grid((HID * HID + 255) / 256, 7);
        k_wt_all<<<wt_grid, 256, 0, stream>>>(W[0], Wm1, W[1], Wm2, W[2], W[3], W[4],
                                              Wt1, Wtm1, Wt2, Wtm2, Wt3, Wt4, Wt5);
    }

    const int MB = N_NODES / QM;  // 625
    dim3 gg2(MB, 1, 2);
    dim3 gg1(MB, 1, 1);
    const int AGG_B = (N_NODES + 3) / 4;

    // Layer 1
    k_gemm5<F_IN><<<gg2, 256, 0, stream>>>(x_bf, Wt1, gat_bf, as_[0], ad_[0], sdbuf,
                                           Wtm1, bm1, big1, N_NODES);
    k_agg<<<AGG_B, 256, 0, stream>>>(gat_bf, sdbuf, off, srcl, bb[0], big1, big1, h_bf);

    // Layer 2
    k_gemm5<HID><<<gg2, 256, 0, stream>>>(h_bf, Wt2, gat_bf, as_[1], ad_[1], sdbuf,
                                          Wtm2, bm2, big2, N_NODES);
    k_agg<<<AGG_B, 256, 0, stream>>>(gat_bf, sdbuf, off, srcl, bb[1], big2, big2, h_bf);

    // Layers 3-5: h = h + relu(gat(h)) in place on big2
    const unsigned short* Wtl[3] = {Wt3, Wt4, Wt5};
    for (int l = 2; l < 5; ++l) {
        k_gemm5<HID><<<gg1, 256, 0, stream>>>(h_bf, Wtl[l - 2], gat_bf, as_[l], ad_[l], sdbuf,
                                              nullptr, nullptr, nullptr, N_NODES);
        unsigned short* mirror = (l < 4) ? h_bf : nullptr;
        k_agg<<<AGG_B, 256, 0, stream>>>(gat_bf, sdbuf, off, srcl, bb[l], big2, big2, mirror);
    }

    // pool + head
    k_pool<<<dim3(G_GRAPHS, HID / 64), 64, 0, stream>>>(big2, batch, pooled);
    k_mlp1<<<dim3(G_GRAPHS, NHID / 64), 64, 0, stream>>>(pooled, Wh1, bh1, z1);
    k_mlp2_ln<<<G_GRAPHS, NOUT, 0, stream>>>(z1, Wh2, bh2, lng, lnb, out);
}